// Round 5
// baseline (422.963 us; speedup 1.0000x reference)
//
#include <hip/hip_runtime.h>
#include <math.h>

#define LSEG 6
#define HH 128
#define WW 128
#define KS 32768
#define CC 12
#define XSPLIT 16
#define XROWS (HH / XSPLIT)   // 8 x-rows per block
#define TPB 256
#define KPT 2                 // k-samples per thread

// Static device workspace (no reliance on ws_size). 16B-aligned: these are
// accessed through float4* casts (global_load_dwordx4 / ds_read_b128).
// g_Bx: [x][y][l][2]  (l-interleaved: 48 contiguous bytes per pixel)
__device__ __align__(16) float g_Bx[HH * WW * LSEG * 2];        // 768 KB
// g_part: [split][k][l][2] partial FBx sums
__device__ __align__(16) float g_part[XSPLIT * KS * LSEG * 2];  // 25 MB

__global__ __launch_bounds__(256) void bx_kernel(const float* __restrict__ img_r,
                                                 const float* __restrict__ img_i,
                                                 const float* __restrict__ sf_r,
                                                 const float* __restrict__ sf_i) {
    int xy = blockIdx.x * blockDim.x + threadIdx.x;     // 0 .. 16383
    if (xy >= HH * WW) return;
    float ir = img_r[xy], ii = img_i[xy];
#pragma unroll
    for (int l = 0; l < LSEG; ++l) {
        float sr = sf_r[l * HH * WW + xy];
        float si = sf_i[l * HH * WW + xy];
        g_Bx[xy * (LSEG * 2) + l * 2 + 0] = sr * ir - si * ii;
        g_Bx[xy * (LSEG * 2) + l * 2 + 1] = sr * ii + si * ir;
    }
}

// KPT k-samples per thread; blockIdx.y selects an 8-row x-slab.
// FBx_partial[l] = sum_{x in slab} Ex[k,x] * (sum_y Bx[l,x,y] * Ey[k,y])
__global__ __launch_bounds__(TPB) void nudft_kernel(const float* __restrict__ trj) {
    __shared__ __align__(16) float smem[WW * LSEG * 2]; // one Bx row: 6 KB

    const int kbase = blockIdx.x * (TPB * KPT) + threadIdx.x;  // k_j = kbase + j*TPB
    const int x0 = blockIdx.y * XROWS;
    const float twopi = 6.28318530717958647692f;

    float exr[KPT], exi[KPT], exsr[KPT], exsi[KPT];
    float eyr0[KPT], eyi0[KPT], eysr[KPT], eysi[KPT];
#pragma unroll
    for (int j = 0; j < KPT; ++j) {
        const int k = kbase + j * TPB;
        const float tx = trj[k * 2 + 0];
        const float ty = trj[k * 2 + 1];
        float ph0 = -twopi * tx * ((float)(x0 - 64) * (1.0f / 128.0f));
        float phs = -twopi * tx * (1.0f / 128.0f);
        sincosf(ph0, &exi[j], &exr[j]);
        sincosf(phs, &exsi[j], &exsr[j]);
        float qh0 = -twopi * ty * (-64.0f * (1.0f / 128.0f));
        float qhs = -twopi * ty * (1.0f / 128.0f);
        sincosf(qh0, &eyi0[j], &eyr0[j]);
        sincosf(qhs, &eysi[j], &eysr[j]);
    }

    float accr[KPT][LSEG], acci[KPT][LSEG];
#pragma unroll
    for (int j = 0; j < KPT; ++j)
#pragma unroll
        for (int l = 0; l < LSEG; ++l) { accr[j][l] = 0.0f; acci[j][l] = 0.0f; }

    for (int xr = 0; xr < XROWS; ++xr) {
        const int x = x0 + xr;
        __syncthreads();   // protect smem reads of previous iteration
        {
            const float4* src = (const float4*)(g_Bx + (size_t)x * (WW * LSEG * 2));
            float4* dst = (float4*)smem;
#pragma unroll
            for (int i = 0; i < 2; ++i) {
                int idx = threadIdx.x + i * TPB;
                if (idx < (WW * LSEG * 2) / 4) dst[idx] = src[idx];
            }
        }
        __syncthreads();

        float ur[KPT][LSEG], ui[KPT][LSEG];
        float eyr[KPT], eyi[KPT];
#pragma unroll
        for (int j = 0; j < KPT; ++j) {
            eyr[j] = eyr0[j]; eyi[j] = eyi0[j];
#pragma unroll
            for (int l = 0; l < LSEG; ++l) { ur[j][l] = 0.0f; ui[j][l] = 0.0f; }
        }

        const float4* s4 = (const float4*)smem;
#pragma unroll 4
        for (int y = 0; y < WW; ++y) {
            float4 b0 = s4[y * 3 + 0];   // l0.r l0.i l1.r l1.i
            float4 b1 = s4[y * 3 + 1];   // l2.r l2.i l3.r l3.i
            float4 b2 = s4[y * 3 + 2];   // l4.r l4.i l5.r l5.i
#pragma unroll
            for (int j = 0; j < KPT; ++j) {
                float er = eyr[j], ei = eyi[j];
                ur[j][0] = fmaf(b0.x, er, fmaf(-b0.y, ei, ur[j][0]));
                ui[j][0] = fmaf(b0.x, ei, fmaf( b0.y, er, ui[j][0]));
                ur[j][1] = fmaf(b0.z, er, fmaf(-b0.w, ei, ur[j][1]));
                ui[j][1] = fmaf(b0.z, ei, fmaf( b0.w, er, ui[j][1]));
                ur[j][2] = fmaf(b1.x, er, fmaf(-b1.y, ei, ur[j][2]));
                ui[j][2] = fmaf(b1.x, ei, fmaf( b1.y, er, ui[j][2]));
                ur[j][3] = fmaf(b1.z, er, fmaf(-b1.w, ei, ur[j][3]));
                ui[j][3] = fmaf(b1.z, ei, fmaf( b1.w, er, ui[j][3]));
                ur[j][4] = fmaf(b2.x, er, fmaf(-b2.y, ei, ur[j][4]));
                ui[j][4] = fmaf(b2.x, ei, fmaf( b2.y, er, ui[j][4]));
                ur[j][5] = fmaf(b2.z, er, fmaf(-b2.w, ei, ur[j][5]));
                ui[j][5] = fmaf(b2.z, ei, fmaf( b2.w, er, ui[j][5]));
                float ner = fmaf(er, eysr[j], -ei * eysi[j]);
                float nei = fmaf(er, eysi[j],  ei * eysr[j]);
                eyr[j] = ner; eyi[j] = nei;
            }
        }

#pragma unroll
        for (int j = 0; j < KPT; ++j) {
#pragma unroll
            for (int l = 0; l < LSEG; ++l) {
                accr[j][l] = fmaf(exr[j], ur[j][l], fmaf(-exi[j], ui[j][l], accr[j][l]));
                acci[j][l] = fmaf(exr[j], ui[j][l], fmaf( exi[j], ur[j][l], acci[j][l]));
            }
            float nxr = fmaf(exr[j], exsr[j], -exi[j] * exsi[j]);
            float nxi = fmaf(exr[j], exsi[j],  exi[j] * exsr[j]);
            exr[j] = nxr; exi[j] = nxi;
        }
    }

#pragma unroll
    for (int j = 0; j < KPT; ++j) {
        const int k = kbase + j * TPB;
        float4* outp = (float4*)(g_part + ((size_t)blockIdx.y * KS + k) * (LSEG * 2));
        outp[0] = make_float4(accr[j][0], acci[j][0], accr[j][1], acci[j][1]);
        outp[1] = make_float4(accr[j][2], acci[j][2], accr[j][3], acci[j][3]);
        outp[2] = make_float4(accr[j][4], acci[j][4], accr[j][5], acci[j][5]);
    }
}

// Reduce the XSPLIT partials and apply the temporal basis tf (L,C,K).
__global__ __launch_bounds__(256) void combine_kernel(const float* __restrict__ tf_r,
                                                      const float* __restrict__ tf_i,
                                                      float* __restrict__ out) {
    int k = blockIdx.x * blockDim.x + threadIdx.x;      // 0..KS-1
    if (k >= KS) return;

    float fr[LSEG], fi[LSEG];
#pragma unroll
    for (int l = 0; l < LSEG; ++l) { fr[l] = 0.0f; fi[l] = 0.0f; }

#pragma unroll
    for (int s = 0; s < XSPLIT; ++s) {
        const float4* p = (const float4*)(g_part + ((size_t)s * KS + k) * (LSEG * 2));
        float4 a = p[0], b = p[1], c = p[2];
        fr[0] += a.x; fi[0] += a.y; fr[1] += a.z; fi[1] += a.w;
        fr[2] += b.x; fi[2] += b.y; fr[3] += b.z; fi[3] += b.w;
        fr[4] += c.x; fi[4] += c.y; fr[5] += c.z; fi[5] += c.w;
    }

#pragma unroll
    for (int c = 0; c < CC; ++c) {
        float outr = 0.0f, outi = 0.0f;
#pragma unroll
        for (int l = 0; l < LSEG; ++l) {
            float tr = tf_r[((size_t)l * CC + c) * KS + k];
            float ti = tf_i[((size_t)l * CC + c) * KS + k];
            outr = fmaf(fr[l], tr, fmaf(-fi[l], ti, outr));
            outi = fmaf(fr[l], ti, fmaf( fi[l], tr, outi));
        }
        float2* o = (float2*)(out + ((size_t)c * KS + k) * 2);
        *o = make_float2(outr, outi);
    }
}

extern "C" void kernel_launch(void* const* d_in, const int* in_sizes, int n_in,
                              void* d_out, int out_size, void* d_ws, size_t ws_size,
                              hipStream_t stream) {
    const float* img_r = (const float*)d_in[0];
    const float* img_i = (const float*)d_in[1];
    const float* sf_r  = (const float*)d_in[2];
    const float* sf_i  = (const float*)d_in[3];
    const float* tf_r  = (const float*)d_in[4];
    const float* tf_i  = (const float*)d_in[5];
    const float* trj   = (const float*)d_in[6];
    float* out = (float*)d_out;

    bx_kernel<<<(HH * WW + 255) / 256, 256, 0, stream>>>(img_r, img_i, sf_r, sf_i);
    nudft_kernel<<<dim3(KS / (TPB * KPT), XSPLIT), TPB, 0, stream>>>(trj);
    combine_kernel<<<(KS + 255) / 256, 256, 0, stream>>>(tf_r, tf_i, out);
}

// Round 7
// 247.853 us; speedup vs baseline: 1.7065x; 1.7065x over previous
//
#include <hip/hip_runtime.h>
#include <math.h>

#define LSEG 6
#define HH 128
#define WW 128
#define KS 32768
#define CC 12
#define XSPLIT 16             // x-groups (8 x's each) -> partial FBx splits
#define TWOPI 6.28318530717958647692f

typedef __attribute__((ext_vector_type(4))) float f32x4;
typedef __attribute__((ext_vector_type(8))) short s16x8;

// ---------- static device workspace ----------
// A (Ey) in MFMA-fragment-tiled order: [mt 2048][kt 8][lane 64][j 8] bf16, hi/lo planes
__device__ __align__(16) unsigned short g_Ahi[(size_t)2048 * 8 * 512];   // 16.78 MB
__device__ __align__(16) unsigned short g_Alo[(size_t)2048 * 8 * 512];   // 16.78 MB
// B (Bx rearranged) fragment-tiled per x-group: [xg 16][nt 6][kt 8][lane 64][j 8]
__device__ __align__(16) unsigned short g_Bhi[(size_t)16 * 6 * 8 * 512]; // 0.79 MB
__device__ __align__(16) unsigned short g_Blo[(size_t)16 * 6 * 8 * 512]; // 0.79 MB
// Ex complex fp32 table [k][x][2]
__device__ __align__(16) float g_Ex[(size_t)KS * 128 * 2];               // 33.5 MB
// partial FBx sums [xg][k][l][2]
__device__ __align__(16) float g_part[(size_t)XSPLIT * KS * LSEG * 2];   // 25 MB

// ---------- helpers ----------
__device__ inline unsigned short bf16_rtne(float v) {
    unsigned u = __float_as_uint(v);
    unsigned r = u + 0x7FFFu + ((u >> 16) & 1u);
    return (unsigned short)(r >> 16);
}
__device__ inline float bf16_f(unsigned short h) {
    return __uint_as_float(((unsigned)h) << 16);
}

// ---------- table kernels ----------
// Ey[k,y] = exp(-2pi*i * ty * (y-64)/128) -> split hi/lo bf16, fragment-tiled
__global__ __launch_bounds__(256) void ey_kernel(const float* __restrict__ trj) {
    int t = blockIdx.x * 256 + threadIdx.x;        // 0 .. 32768*128-1
    int k = t >> 7, y = t & 127;
    float ty = trj[k * 2 + 1];
    float ph = -TWOPI * ty * ((float)(y - 64) * (1.0f / 128.0f));
    float s, c;
    sincosf(ph, &s, &c);
    unsigned short chi = bf16_rtne(c); unsigned short clo = bf16_rtne(c - bf16_f(chi));
    unsigned short shi = bf16_rtne(s); unsigned short slo = bf16_rtne(s - bf16_f(shi));
    // element (row=k, r=2y+{0,1}) -> tile (mt=k>>4, kt=y>>4), lane=(k&15)|(((y>>2)&3)<<4), j=(y&3)*2
    int mt = k >> 4, kt = y >> 4;
    int lane = (k & 15) | (((y >> 2) & 3) << 4);
    size_t dw = (size_t)(mt * 8 + kt) * 256 + lane * 4 + (y & 3);   // dword index
    ((unsigned*)g_Ahi)[dw] = (unsigned)chi | ((unsigned)shi << 16); // j=cos(real), j+1=sin(imag)
    ((unsigned*)g_Alo)[dw] = (unsigned)clo | ((unsigned)slo << 16);
}

// Ex[k,x] = exp(-2pi*i * tx * (x-64)/128) as fp32 complex
__global__ __launch_bounds__(256) void ex_kernel(const float* __restrict__ trj) {
    int t = blockIdx.x * 256 + threadIdx.x;
    int k = t >> 7, x = t & 127;
    float tx = trj[k * 2 + 0];
    float ph = -TWOPI * tx * ((float)(x - 64) * (1.0f / 128.0f));
    float s, c;
    sincosf(ph, &s, &c);
    ((float2*)g_Ex)[(size_t)k * 128 + x] = make_float2(c, s);
}

// B matrix: r=2y+cy (256), per-xg cols nl = m*8+xi (96), m=2l+c'
// B[2y, c'=0]=Bxr  B[2y, c'=1]=Bxi  B[2y+1, c'=0]=-Bxi  B[2y+1, c'=1]=Bxr
__global__ __launch_bounds__(256) void b_kernel(const float* __restrict__ img_r,
                                                const float* __restrict__ img_i,
                                                const float* __restrict__ sf_r,
                                                const float* __restrict__ sf_i) {
    int t = blockIdx.x * 256 + threadIdx.x;        // 0 .. 16*256*96-1 = 393215
    int xg = t / 24576; int rem = t - xg * 24576;
    int r = rem / 96;   int nl = rem - r * 96;
    int y = r >> 1, cy = r & 1;
    int m = nl >> 3, xi = nl & 7;
    int x = xg * 8 + xi, l = m >> 1, cp = m & 1;
    int pix = x * 128 + y;
    float ir = img_r[pix], ii = img_i[pix];
    float sr = sf_r[l * 16384 + pix], si = sf_i[l * 16384 + pix];
    float br = sr * ir - si * ii;
    float bi = sr * ii + si * ir;
    float val = (cy == 0) ? (cp == 0 ? br : bi) : (cp == 0 ? -bi : br);
    unsigned short hi = bf16_rtne(val);
    unsigned short lo = bf16_rtne(val - bf16_f(hi));
    int nt = nl >> 4, c16 = nl & 15;
    int kt = r >> 5, lane = c16 | (((r >> 3) & 3) << 4), j = r & 7;
    size_t idx = (size_t)((xg * 6 + nt) * 8 + kt) * 512 + lane * 8 + j;
    g_Bhi[idx] = hi;
    g_Blo[idx] = lo;
}

// ---------- main GEMM: C[k, (x,l)] = sum_r Ey[k,r]*B[r,(x,l)], fused Ex epilogue ----------
// grid: (xg 16, mb 256); block 256 = 4 waves; wave w owns M-rows [mb*128+w*32, +32)
__global__ __launch_bounds__(256) void gemm_kernel() {
    __shared__ __align__(16) unsigned short ldsA[2 * 8 * 512];   // 16 KB: [plane][mt 8][512]
    __shared__ __align__(16) unsigned short ldsB[2 * 6 * 512];   // 12 KB: [plane][nt 6][512]

    const int tid = threadIdx.x;
    const int xg = blockIdx.x, mb = blockIdx.y;
    const int w = tid >> 6, lane = tid & 63;

    f32x4 acc[2][6];
#pragma unroll
    for (int am = 0; am < 2; ++am)
#pragma unroll
        for (int nt = 0; nt < 6; ++nt) acc[am][nt] = (f32x4)0.0f;

    for (int kt = 0; kt < 8; ++kt) {
        __syncthreads();   // protect previous iteration's frag reads
        // stage A: 8 mt-tiles x 2 planes = 1024 16B-units
#pragma unroll
        for (int i = 0; i < 4; ++i) {
            int u = tid + i * 256;
            int plane = u >> 9, mtl = (u >> 6) & 7, ch = u & 63;
            const unsigned short* src = (plane ? g_Alo : g_Ahi)
                + (size_t)((mb * 8 + mtl) * 8 + kt) * 512 + ch * 8;
            *(float4*)&ldsA[((plane << 3) + mtl) * 512 + ch * 8] = *(const float4*)src;
        }
        // stage B: 6 nt-tiles x 2 planes = 768 16B-units
#pragma unroll
        for (int i = 0; i < 3; ++i) {
            int u = tid + i * 256;
            int plane = (u >= 384) ? 1 : 0;
            int ntl = (u - plane * 384) >> 6, ch = u & 63;
            const unsigned short* src = (plane ? g_Blo : g_Bhi)
                + (size_t)((xg * 6 + ntl) * 8 + kt) * 512 + ch * 8;
            *(float4*)&ldsB[(plane * 6 + ntl) * 512 + ch * 8] = *(const float4*)src;
        }
        __syncthreads();

        s16x8 aH[2], aL[2];
#pragma unroll
        for (int am = 0; am < 2; ++am) {
            aH[am] = *(const s16x8*)&ldsA[(0 * 8 + (w * 2 + am)) * 512 + lane * 8];
            aL[am] = *(const s16x8*)&ldsA[(1 * 8 + (w * 2 + am)) * 512 + lane * 8];
        }
#pragma unroll
        for (int nt = 0; nt < 6; ++nt) {
            s16x8 bH = *(const s16x8*)&ldsB[(0 * 6 + nt) * 512 + lane * 8];
            s16x8 bL = *(const s16x8*)&ldsB[(1 * 6 + nt) * 512 + lane * 8];
#pragma unroll
            for (int am = 0; am < 2; ++am) {
                acc[am][nt] = __builtin_amdgcn_mfma_f32_16x16x32_bf16(aH[am], bH, acc[am][nt], 0, 0, 0);
                acc[am][nt] = __builtin_amdgcn_mfma_f32_16x16x32_bf16(aH[am], bL, acc[am][nt], 0, 0, 0);
                acc[am][nt] = __builtin_amdgcn_mfma_f32_16x16x32_bf16(aL[am], bH, acc[am][nt], 0, 0, 0);
            }
        }
    }

    // epilogue: multiply by Ex[k,x], reduce over the 8 x's, write partial FBx
    // C/D layout: col = lane&15, row = (lane>>4)*4 + reg   [m89-verified]
    const int c16 = lane & 15, xi = c16 & 7, cpbit = c16 >> 3;
    const int rowg = lane >> 4;
    const int x = xg * 8 + xi;
#pragma unroll
    for (int am = 0; am < 2; ++am) {
#pragma unroll
        for (int reg = 0; reg < 4; ++reg) {
            int krow = mb * 128 + (w * 2 + am) * 16 + rowg * 4 + reg;
            float2 e = ((const float2*)g_Ex)[(size_t)krow * 128 + x];
#pragma unroll
            for (int nt = 0; nt < 6; ++nt) {
                float tv = acc[am][nt][reg];
                float pv = __shfl_xor(tv, 8);        // complex partner (other c')
                float v = cpbit ? fmaf(e.x, tv, e.y * pv)      // imag: Exr*Ti + Exi*Tr
                                : fmaf(e.x, tv, -e.y * pv);    // real: Exr*Tr - Exi*Ti
                v += __shfl_xor(v, 1);
                v += __shfl_xor(v, 2);
                v += __shfl_xor(v, 4);               // sum over 8 x's
                if (xi == 0) {
                    int m = nt * 2 + cpbit;          // m = 2l + c'
                    g_part[((size_t)xg * KS + krow) * 12 + m] = v;
                }
            }
        }
    }
}

// ---------- reduce partials + temporal basis (unchanged from passing version) ----------
__global__ __launch_bounds__(256) void combine_kernel(const float* __restrict__ tf_r,
                                                      const float* __restrict__ tf_i,
                                                      float* __restrict__ out) {
    int k = blockIdx.x * blockDim.x + threadIdx.x;
    if (k >= KS) return;

    float fr[LSEG], fi[LSEG];
#pragma unroll
    for (int l = 0; l < LSEG; ++l) { fr[l] = 0.0f; fi[l] = 0.0f; }

#pragma unroll
    for (int s = 0; s < XSPLIT; ++s) {
        const float4* p = (const float4*)(g_part + ((size_t)s * KS + k) * (LSEG * 2));
        float4 a = p[0], b = p[1], c = p[2];
        fr[0] += a.x; fi[0] += a.y; fr[1] += a.z; fi[1] += a.w;
        fr[2] += b.x; fi[2] += b.y; fr[3] += b.z; fi[3] += b.w;
        fr[4] += c.x; fi[4] += c.y; fr[5] += c.z; fi[5] += c.w;
    }

#pragma unroll
    for (int c = 0; c < CC; ++c) {
        float outr = 0.0f, outi = 0.0f;
#pragma unroll
        for (int l = 0; l < LSEG; ++l) {
            float tr = tf_r[((size_t)l * CC + c) * KS + k];
            float ti = tf_i[((size_t)l * CC + c) * KS + k];
            outr = fmaf(fr[l], tr, fmaf(-fi[l], ti, outr));
            outi = fmaf(fr[l], ti, fmaf( fi[l], tr, outi));
        }
        float2* o = (float2*)(out + ((size_t)c * KS + k) * 2);
        *o = make_float2(outr, outi);
    }
}

extern "C" void kernel_launch(void* const* d_in, const int* in_sizes, int n_in,
                              void* d_out, int out_size, void* d_ws, size_t ws_size,
                              hipStream_t stream) {
    const float* img_r = (const float*)d_in[0];
    const float* img_i = (const float*)d_in[1];
    const float* sf_r  = (const float*)d_in[2];
    const float* sf_i  = (const float*)d_in[3];
    const float* tf_r  = (const float*)d_in[4];
    const float* tf_i  = (const float*)d_in[5];
    const float* trj   = (const float*)d_in[6];
    float* out = (float*)d_out;

    ey_kernel<<<(KS * 128) / 256, 256, 0, stream>>>(trj);
    ex_kernel<<<(KS * 128) / 256, 256, 0, stream>>>(trj);
    b_kernel<<<(16 * 256 * 96) / 256, 256, 0, stream>>>(img_r, img_i, sf_r, sf_i);
    gemm_kernel<<<dim3(16, 256), 256, 0, stream>>>();
    combine_kernel<<<(KS + 255) / 256, 256, 0, stream>>>(tf_r, tf_i, out);
}

// Round 10
// 218.766 us; speedup vs baseline: 1.9334x; 1.1330x over previous
//
#include <hip/hip_runtime.h>
#include <math.h>

#define LSEG 6
#define KS 32768
#define CC 12
#define XSPLIT 16
#define TWOPI 6.28318530717958647692f

typedef __attribute__((ext_vector_type(4))) float f32x4;
typedef __attribute__((ext_vector_type(8))) short s16x8;

// B fragment-tiled per x-group: [xg 16][nt 6][kt 8][lane 64][j 8], hi/lo planes
__device__ __align__(16) unsigned short g_Bhi[(size_t)16 * 6 * 8 * 512]; // 0.79 MB
__device__ __align__(16) unsigned short g_Blo[(size_t)16 * 6 * 8 * 512]; // 0.79 MB
// partial FBx sums [xg][k][l][2]
__device__ __align__(16) float g_part[(size_t)XSPLIT * KS * LSEG * 2];   // 25 MB

// ---------- helpers ----------
__device__ inline unsigned bf16_rtne_bits(float v) {
    unsigned u = __float_as_uint(v);
    return (u + 0x7FFFu + ((u >> 16) & 1u)) >> 16;   // 16-bit result in low bits
}
__device__ inline float bf16_f_bits(unsigned h16) {
    return __uint_as_float(h16 << 16);
}

// B matrix: rows r=2y+cy (256), per-xg cols nl = m*8+xi (96), m=2l+c'
// B[2y, c'=0]=Bxr  B[2y, c'=1]=Bxi  B[2y+1, c'=0]=-Bxi  B[2y+1, c'=1]=Bxr
__global__ __launch_bounds__(256) void b_kernel(const float* __restrict__ img_r,
                                                const float* __restrict__ img_i,
                                                const float* __restrict__ sf_r,
                                                const float* __restrict__ sf_i) {
    int t = blockIdx.x * 256 + threadIdx.x;        // 0 .. 16*256*96-1
    int xg = t / 24576; int rem = t - xg * 24576;
    int r = rem / 96;   int nl = rem - r * 96;
    int y = r >> 1, cy = r & 1;
    int m = nl >> 3, xi = nl & 7;
    int x = xg * 8 + xi, l = m >> 1, cp = m & 1;
    int pix = x * 128 + y;
    float ir = img_r[pix], ii = img_i[pix];
    float sr = sf_r[l * 16384 + pix], si = sf_i[l * 16384 + pix];
    float br = sr * ir - si * ii;
    float bi = sr * ii + si * ir;
    float val = (cy == 0) ? (cp == 0 ? br : bi) : (cp == 0 ? -bi : br);
    unsigned hi = bf16_rtne_bits(val);
    unsigned lo = bf16_rtne_bits(val - bf16_f_bits(hi));
    int nt = nl >> 4, c16 = nl & 15;
    int kt = r >> 5, lane = c16 | (((r >> 3) & 3) << 4), j = r & 7;
    size_t idx = (size_t)((xg * 6 + nt) * 8 + kt) * 512 + lane * 8 + j;
    g_Bhi[idx] = (unsigned short)hi;
    g_Blo[idx] = (unsigned short)lo;
}

// ---------- fused GEMM: A (Ey) generated in-register, Ex in epilogue ----------
// grid (xg 16, mb 256), 256 thr = 4 waves, wave owns rows [mb*128+w*32, +32)
__global__ __launch_bounds__(256) void gemm2_kernel(const float* __restrict__ trj) {
    __shared__ __align__(16) unsigned short ldsB[2][2 * 6 * 512];  // dbuf, 12 KB each

    const int tid = threadIdx.x;
    const int xg = blockIdx.x, mb = blockIdx.y;
    const int w = tid >> 6, lane = tid & 63;
    const int g = lane >> 4;

    // per-row Ey recurrence state (2 rows per lane: am = 0,1)
    float cr[2], ci[2], d1r[2], d1i[2], d16r[2], d16i[2];
#pragma unroll
    for (int am = 0; am < 2; ++am) {
        int krow = mb * 128 + w * 32 + am * 16 + (lane & 15);
        float ty = trj[krow * 2 + 1];
        float step = -TWOPI * ty * (1.0f / 128.0f);   // phase(y) = step*(y-64)
        sincosf(step * (float)(g * 4 - 64), &ci[am], &cr[am]);
        sincosf(step, &d1i[am], &d1r[am]);
        sincosf(step * 16.0f, &d16i[am], &d16r[am]);
    }

    f32x4 acc[2][6];
#pragma unroll
    for (int am = 0; am < 2; ++am)
#pragma unroll
        for (int nt = 0; nt < 6; ++nt) acc[am][nt] = (f32x4)0.0f;

    // stage B(kt) into ldsB[buf]
    auto stage = [&](int buf, int kt) {
#pragma unroll
        for (int i = 0; i < 3; ++i) {
            int u = tid + i * 256;
            int p = (u >= 384) ? 1 : 0;
            int ntl = (u - p * 384) >> 6, ch = u & 63;
            const unsigned short* src = (p ? g_Blo : g_Bhi)
                + (size_t)((xg * 6 + ntl) * 8 + kt) * 512 + ch * 8;
            *(float4*)&ldsB[buf][u * 8] = *(const float4*)src;
        }
    };

    stage(0, 0);

    for (int kt = 0; kt < 8; ++kt) {
        __syncthreads();                      // buf[kt&1] ready; prev reads done
        if (kt < 7) stage((kt + 1) & 1, kt + 1);

        // generate A-fragments for this kt (hi/lo split of Ey)
        s16x8 aH[2], aL[2];
#pragma unroll
        for (int am = 0; am < 2; ++am) {
            float c0 = cr[am], s0 = ci[am];
            float c1 = c0 * d1r[am] - s0 * d1i[am], s1 = c0 * d1i[am] + s0 * d1r[am];
            float c2 = c1 * d1r[am] - s1 * d1i[am], s2 = c1 * d1i[am] + s1 * d1r[am];
            float c3 = c2 * d1r[am] - s2 * d1i[am], s3 = c2 * d1i[am] + s2 * d1r[am];
            cr[am] = c0 * d16r[am] - s0 * d16i[am];           // advance to next kt
            ci[am] = c0 * d16i[am] + s0 * d16r[am];
            float vals[8] = {c0, s0, c1, s1, c2, s2, c3, s3};
            union { s16x8 v; unsigned u[4]; } H, L;
#pragma unroll
            for (int p = 0; p < 4; ++p) {
                float a = vals[2 * p], b = vals[2 * p + 1];
                unsigned ha = bf16_rtne_bits(a), hb = bf16_rtne_bits(b);
                H.u[p] = ha | (hb << 16);
                unsigned la = bf16_rtne_bits(a - bf16_f_bits(ha));
                unsigned lb = bf16_rtne_bits(b - bf16_f_bits(hb));
                L.u[p] = la | (lb << 16);
            }
            aH[am] = H.v; aL[am] = L.v;
        }

        const unsigned short* bb = ldsB[kt & 1];
#pragma unroll
        for (int nt = 0; nt < 6; ++nt) {
            s16x8 bH = *(const s16x8*)&bb[(0 * 6 + nt) * 512 + lane * 8];
            s16x8 bL = *(const s16x8*)&bb[(1 * 6 + nt) * 512 + lane * 8];
#pragma unroll
            for (int am = 0; am < 2; ++am) {
                acc[am][nt] = __builtin_amdgcn_mfma_f32_16x16x32_bf16(aH[am], bH, acc[am][nt], 0, 0, 0);
                acc[am][nt] = __builtin_amdgcn_mfma_f32_16x16x32_bf16(aH[am], bL, acc[am][nt], 0, 0, 0);
                acc[am][nt] = __builtin_amdgcn_mfma_f32_16x16x32_bf16(aL[am], bH, acc[am][nt], 0, 0, 0);
            }
        }
    }

    // epilogue: Ex on the fly, reduce over 8 x's, write partial FBx
    // C/D layout: col = lane&15, row = (lane>>4)*4 + reg  [m89-verified, proven round 7]
    const int c16 = lane & 15, xi = c16 & 7, cpbit = c16 >> 3;
    const int rowg = lane >> 4;
    const int x = xg * 8 + xi;
    const float xf = (float)(x - 64) * (1.0f / 128.0f);
#pragma unroll
    for (int am = 0; am < 2; ++am) {
#pragma unroll
        for (int reg = 0; reg < 4; ++reg) {
            int krow = mb * 128 + w * 32 + am * 16 + rowg * 4 + reg;
            float tx = trj[krow * 2 + 0];
            float er, ei;
            sincosf(-TWOPI * tx * xf, &ei, &er);
#pragma unroll
            for (int nt = 0; nt < 6; ++nt) {
                float tv = acc[am][nt][reg];
                float pv = __shfl_xor(tv, 8);            // complex partner (other c')
                float v = cpbit ? fmaf(er, tv, ei * pv)  // imag: Exr*Ti + Exi*Tr
                                : fmaf(er, tv, -ei * pv); // real: Exr*Tr - Exi*Ti
                v += __shfl_xor(v, 1);
                v += __shfl_xor(v, 2);
                v += __shfl_xor(v, 4);                   // sum over 8 x's
                if (xi == 0) {
                    int m = nt * 2 + cpbit;              // m = 2l + c'
                    g_part[((size_t)xg * KS + krow) * 12 + m] = v;
                }
            }
        }
    }
}

// ---------- reduce partials + temporal basis (unchanged, proven) ----------
__global__ __launch_bounds__(256) void combine_kernel(const float* __restrict__ tf_r,
                                                      const float* __restrict__ tf_i,
                                                      float* __restrict__ out) {
    int k = blockIdx.x * blockDim.x + threadIdx.x;
    if (k >= KS) return;

    float fr[LSEG], fi[LSEG];
#pragma unroll
    for (int l = 0; l < LSEG; ++l) { fr[l] = 0.0f; fi[l] = 0.0f; }

#pragma unroll
    for (int s = 0; s < XSPLIT; ++s) {
        const float4* p = (const float4*)(g_part + ((size_t)s * KS + k) * (LSEG * 2));
        float4 a = p[0], b = p[1], c = p[2];
        fr[0] += a.x; fi[0] += a.y; fr[1] += a.z; fi[1] += a.w;
        fr[2] += b.x; fi[2] += b.y; fr[3] += b.z; fi[3] += b.w;
        fr[4] += c.x; fi[4] += c.y; fr[5] += c.z; fi[5] += c.w;
    }

#pragma unroll
    for (int c = 0; c < CC; ++c) {
        float outr = 0.0f, outi = 0.0f;
#pragma unroll
        for (int l = 0; l < LSEG; ++l) {
            float tr = tf_r[((size_t)l * CC + c) * KS + k];
            float ti = tf_i[((size_t)l * CC + c) * KS + k];
            outr = fmaf(fr[l], tr, fmaf(-fi[l], ti, outr));
            outi = fmaf(fr[l], ti, fmaf( fi[l], tr, outi));
        }
        float2* o = (float2*)(out + ((size_t)c * KS + k) * 2);
        *o = make_float2(outr, outi);
    }
}

extern "C" void kernel_launch(void* const* d_in, const int* in_sizes, int n_in,
                              void* d_out, int out_size, void* d_ws, size_t ws_size,
                              hipStream_t stream) {
    const float* img_r = (const float*)d_in[0];
    const float* img_i = (const float*)d_in[1];
    const float* sf_r  = (const float*)d_in[2];
    const float* sf_i  = (const float*)d_in[3];
    const float* tf_r  = (const float*)d_in[4];
    const float* tf_i  = (const float*)d_in[5];
    const float* trj   = (const float*)d_in[6];
    float* out = (float*)d_out;

    b_kernel<<<(16 * 256 * 96) / 256, 256, 0, stream>>>(img_r, img_i, sf_r, sf_i);
    gemm2_kernel<<<dim3(16, 256), 256, 0, stream>>>(trj);
    combine_kernel<<<(KS + 255) / 256, 256, 0, stream>>>(tf_r, tf_i, out);
}

// Round 14
// 215.065 us; speedup vs baseline: 1.9667x; 1.0172x over previous
//
#include <hip/hip_runtime.h>
#include <hip/hip_bf16.h>
#include <math.h>

#define LSEG 6
#define KS 32768
#define CC 12
#define XSPLIT 16
#define TWOPI 6.28318530717958647692f

typedef __attribute__((ext_vector_type(4))) float f32x4;
typedef __attribute__((ext_vector_type(8))) short s16x8;

// B fragment-tiled per x-group: [xg 16][nt 6][kt 8][lane 64][j 8], hi/lo planes
__device__ __align__(16) unsigned short g_Bhi[(size_t)16 * 6 * 8 * 512]; // 0.79 MB
__device__ __align__(16) unsigned short g_Blo[(size_t)16 * 6 * 8 * 512]; // 0.79 MB
// partial FBx sums [xg][k][l][2]
__device__ __align__(16) float g_part[(size_t)XSPLIT * KS * LSEG * 2];   // 25 MB

// ---------- helpers ----------
__device__ inline unsigned bf16_rtne_bits(float v) {
    unsigned u = __float_as_uint(v);
    return (u + 0x7FFFu + ((u >> 16) & 1u)) >> 16;
}
__device__ inline float bf16_f_bits(unsigned h16) {
    return __uint_as_float(h16 << 16);
}
// packed f32x2 -> bf16x2 via scalar casts (compiler fuses to v_cvt_pk_bf16_f32, m240)
__device__ inline unsigned cvt_pk2(float a, float b) {
    __hip_bfloat16 ha = __float2bfloat16(a);
    __hip_bfloat16 hb = __float2bfloat16(b);
    union { __hip_bfloat16 h; unsigned short s; } ua, ub;
    ua.h = ha; ub.h = hb;
    return (unsigned)ua.s | ((unsigned)ub.s << 16);
}
// async global->LDS, 16B per lane (dest = wave-uniform base + lane*16)
__device__ inline void load_lds16(const void* g, void* l) {
    __builtin_amdgcn_global_load_lds(
        (const __attribute__((address_space(1))) unsigned int*)g,
        (__attribute__((address_space(3))) unsigned int*)l, 16, 0, 0);
}

// B matrix: rows r=2y+cy (256), per-xg cols nl = m*8+xi (96), m=2l+c'
// B[2y, c'=0]=Bxr  B[2y, c'=1]=Bxi  B[2y+1, c'=0]=-Bxi  B[2y+1, c'=1]=Bxr
__global__ __launch_bounds__(256) void b_kernel(const float* __restrict__ img_r,
                                                const float* __restrict__ img_i,
                                                const float* __restrict__ sf_r,
                                                const float* __restrict__ sf_i) {
    int t = blockIdx.x * 256 + threadIdx.x;
    int xg = t / 24576; int rem = t - xg * 24576;
    int r = rem / 96;   int nl = rem - r * 96;
    int y = r >> 1, cy = r & 1;
    int m = nl >> 3, xi = nl & 7;
    int x = xg * 8 + xi, l = m >> 1, cp = m & 1;
    int pix = x * 128 + y;
    float ir = img_r[pix], ii = img_i[pix];
    float sr = sf_r[l * 16384 + pix], si = sf_i[l * 16384 + pix];
    float br = sr * ir - si * ii;
    float bi = sr * ii + si * ir;
    float val = (cy == 0) ? (cp == 0 ? br : bi) : (cp == 0 ? -bi : br);
    unsigned hi = bf16_rtne_bits(val);
    unsigned lo = bf16_rtne_bits(val - bf16_f_bits(hi));
    int nt = nl >> 4, c16 = nl & 15;
    int kt = r >> 5, lane = c16 | (((r >> 3) & 3) << 4), j = r & 7;
    size_t idx = (size_t)((xg * 6 + nt) * 8 + kt) * 512 + lane * 8 + j;
    g_Bhi[idx] = (unsigned short)hi;
    g_Blo[idx] = (unsigned short)lo;
}

// ---------- fused GEMM: 2 x-groups per block, A (Ey) in-register, Ex epilogue ----
// grid (bx 8, mb 256), 256 thr = 4 waves; wave owns rows [mb*128+w*32, +32)
__global__ __launch_bounds__(256, 2) void gemm3_kernel(const float* __restrict__ trj) {
    // [buf][xg2][p*6+ntl][512 shorts] = 48 KB
    __shared__ __align__(16) unsigned short ldsB[2][2][12][512];

    const int tid = threadIdx.x;
    const int bx = blockIdx.x, mb = blockIdx.y;
    const int w = tid >> 6, lane = tid & 63;
    const int g = lane >> 4;

    // per-row Ey recurrence state (2 rows per lane: am = 0,1)
    float cr[2], ci[2], d1r[2], d1i[2], d16r[2], d16i[2];
#pragma unroll
    for (int am = 0; am < 2; ++am) {
        int krow = mb * 128 + w * 32 + am * 16 + (lane & 15);
        float ty = trj[krow * 2 + 1];
        float step = -TWOPI * ty * (1.0f / 128.0f);
        sincosf(step * (float)(g * 4 - 64), &ci[am], &cr[am]);
        sincosf(step, &d1i[am], &d1r[am]);
        sincosf(step * 16.0f, &d16i[am], &d16r[am]);
    }

    f32x4 acc[2][2][6];   // [am][xg2][nt]
#pragma unroll
    for (int am = 0; am < 2; ++am)
#pragma unroll
        for (int x2 = 0; x2 < 2; ++x2)
#pragma unroll
            for (int nt = 0; nt < 6; ++nt) acc[am][x2][nt] = (f32x4)0.0f;

    // stage B(kt) for both xg's via global_load_lds (wave-uniform dest)
    auto stage = [&](int buf, int kt) {
#pragma unroll
        for (int i = 0; i < 6; ++i) {
            int seg = w + i * 4;                 // 0..23, wave-uniform
            int xg2 = seg / 12, rem = seg - xg2 * 12;
            int p = rem / 6, ntl = rem - p * 6;
            int xg = bx * 2 + xg2;
            const unsigned short* src = (p ? g_Blo : g_Bhi)
                + (size_t)((xg * 6 + ntl) * 8 + kt) * 512 + lane * 8;
            load_lds16(src, &ldsB[buf][xg2][rem][0]);
        }
    };

    stage(0, 0);

    for (int kt = 0; kt < 8; ++kt) {
        __syncthreads();                  // buf[kt&1] loads drained; prev reads done
        if (kt < 7) stage((kt + 1) & 1, kt + 1);

        // A-fragments for this kt (hi/lo split of Ey, packed cvt)
        s16x8 aH[2], aL[2];
#pragma unroll
        for (int am = 0; am < 2; ++am) {
            float c0 = cr[am], s0 = ci[am];
            float c1 = c0 * d1r[am] - s0 * d1i[am], s1 = c0 * d1i[am] + s0 * d1r[am];
            float c2 = c1 * d1r[am] - s1 * d1i[am], s2 = c1 * d1i[am] + s1 * d1r[am];
            float c3 = c2 * d1r[am] - s2 * d1i[am], s3 = c2 * d1i[am] + s2 * d1r[am];
            cr[am] = c0 * d16r[am] - s0 * d16i[am];
            ci[am] = c0 * d16i[am] + s0 * d16r[am];
            float vals[8] = {c0, s0, c1, s1, c2, s2, c3, s3};
            union { s16x8 v; unsigned u[4]; } H, L;
#pragma unroll
            for (int p = 0; p < 4; ++p) {
                float a = vals[2 * p], b = vals[2 * p + 1];
                unsigned h = cvt_pk2(a, b);
                H.u[p] = h;
                float la = a - bf16_f_bits(h & 0xFFFFu);
                float lb = b - bf16_f_bits(h >> 16);
                L.u[p] = cvt_pk2(la, lb);
            }
            aH[am] = H.v; aL[am] = L.v;
        }

#pragma unroll
        for (int x2 = 0; x2 < 2; ++x2) {
#pragma unroll
            for (int nt = 0; nt < 6; ++nt) {
                s16x8 bH = *(const s16x8*)&ldsB[kt & 1][x2][nt][lane * 8];
                s16x8 bL = *(const s16x8*)&ldsB[kt & 1][x2][6 + nt][lane * 8];
#pragma unroll
                for (int am = 0; am < 2; ++am) {
                    acc[am][x2][nt] = __builtin_amdgcn_mfma_f32_16x16x32_bf16(aH[am], bH, acc[am][x2][nt], 0, 0, 0);
                    acc[am][x2][nt] = __builtin_amdgcn_mfma_f32_16x16x32_bf16(aH[am], bL, acc[am][x2][nt], 0, 0, 0);
                    acc[am][x2][nt] = __builtin_amdgcn_mfma_f32_16x16x32_bf16(aL[am], bH, acc[am][x2][nt], 0, 0, 0);
                }
            }
        }
    }

    // epilogue: Ex on the fly, reduce over 8 x's per xg, write partial FBx
    // C/D layout: col = lane&15, row = (lane>>4)*4 + reg  [m89-verified, proven R7/R10]
    const int c16 = lane & 15, xi = c16 & 7, cpbit = c16 >> 3;
    const int rowg = lane >> 4;
#pragma unroll
    for (int am = 0; am < 2; ++am) {
#pragma unroll
        for (int reg = 0; reg < 4; ++reg) {
            int krow = mb * 128 + w * 32 + am * 16 + rowg * 4 + reg;
            float tx = trj[krow * 2 + 0];
#pragma unroll
            for (int x2 = 0; x2 < 2; ++x2) {
                int xg = bx * 2 + x2;
                int x = xg * 8 + xi;
                float er, ei;
                sincosf(-TWOPI * tx * ((float)(x - 64) * (1.0f / 128.0f)), &ei, &er);
#pragma unroll
                for (int nt = 0; nt < 6; ++nt) {
                    float tv = acc[am][x2][nt][reg];
                    float pv = __shfl_xor(tv, 8);            // complex partner
                    float v = cpbit ? fmaf(er, tv, ei * pv)  // imag
                                    : fmaf(er, tv, -ei * pv);// real
                    v += __shfl_xor(v, 1);
                    v += __shfl_xor(v, 2);
                    v += __shfl_xor(v, 4);                   // sum over 8 x's
                    if (xi == 0) {
                        int m = nt * 2 + cpbit;              // m = 2l + c'
                        g_part[((size_t)xg * KS + krow) * 12 + m] = v;
                    }
                }
            }
        }
    }
}

// ---------- reduce partials + temporal basis (unchanged, proven) ----------
__global__ __launch_bounds__(256) void combine_kernel(const float* __restrict__ tf_r,
                                                      const float* __restrict__ tf_i,
                                                      float* __restrict__ out) {
    int k = blockIdx.x * blockDim.x + threadIdx.x;
    if (k >= KS) return;

    float fr[LSEG], fi[LSEG];
#pragma unroll
    for (int l = 0; l < LSEG; ++l) { fr[l] = 0.0f; fi[l] = 0.0f; }

#pragma unroll
    for (int s = 0; s < XSPLIT; ++s) {
        const float4* p = (const float4*)(g_part + ((size_t)s * KS + k) * (LSEG * 2));
        float4 a = p[0], b = p[1], c = p[2];
        fr[0] += a.x; fi[0] += a.y; fr[1] += a.z; fi[1] += a.w;
        fr[2] += b.x; fi[2] += b.y; fr[3] += b.z; fi[3] += b.w;
        fr[4] += c.x; fi[4] += c.y; fr[5] += c.z; fi[5] += c.w;
    }

#pragma unroll
    for (int c = 0; c < CC; ++c) {
        float outr = 0.0f, outi = 0.0f;
#pragma unroll
        for (int l = 0; l < LSEG; ++l) {
            float tr = tf_r[((size_t)l * CC + c) * KS + k];
            float ti = tf_i[((size_t)l * CC + c) * KS + k];
            outr = fmaf(fr[l], tr, fmaf(-fi[l], ti, outr));
            outi = fmaf(fr[l], ti, fmaf( fi[l], tr, outi));
        }
        float2* o = (float2*)(out + ((size_t)c * KS + k) * 2);
        *o = make_float2(outr, outi);
    }
}

extern "C" void kernel_launch(void* const* d_in, const int* in_sizes, int n_in,
                              void* d_out, int out_size, void* d_ws, size_t ws_size,
                              hipStream_t stream) {
    const float* img_r = (const float*)d_in[0];
    const float* img_i = (const float*)d_in[1];
    const float* sf_r  = (const float*)d_in[2];
    const float* sf_i  = (const float*)d_in[3];
    const float* tf_r  = (const float*)d_in[4];
    const float* tf_i  = (const float*)d_in[5];
    const float* trj   = (const float*)d_in[6];
    float* out = (float*)d_out;

    b_kernel<<<(16 * 256 * 96) / 256, 256, 0, stream>>>(img_r, img_i, sf_r, sf_i);
    gemm3_kernel<<<dim3(8, 256), 256, 0, stream>>>(trj);
    combine_kernel<<<(KS + 255) / 256, 256, 0, stream>>>(tf_r, tf_i, out);
}

// Round 15
// 166.870 us; speedup vs baseline: 2.5347x; 1.2888x over previous
//
#include <hip/hip_runtime.h>
#include <hip/hip_bf16.h>
#include <math.h>

#define LSEG 6
#define KS 32768
#define CC 12
#define XSPLIT 16
#define TWOPI 6.28318530717958647692f

typedef __attribute__((ext_vector_type(4))) float f32x4;
typedef __attribute__((ext_vector_type(8))) short s16x8;

// B fragment-tiled per x-group: [xg 16][nt 6][kt 8][lane 64][j 8], single bf16 plane
__device__ __align__(16) unsigned short g_B[(size_t)16 * 6 * 8 * 512];   // 0.79 MB
// partial FBx sums [xg][k][l][2]
__device__ __align__(16) float g_part[(size_t)XSPLIT * KS * LSEG * 2];   // 25 MB

// ---------- helpers ----------
__device__ inline unsigned bf16_rtne_bits(float v) {
    unsigned u = __float_as_uint(v);
    return (u + 0x7FFFu + ((u >> 16) & 1u)) >> 16;
}
// packed f32x2 -> bf16x2 via scalar casts (compiler fuses to v_cvt_pk_bf16_f32)
__device__ inline unsigned cvt_pk2(float a, float b) {
    __hip_bfloat16 ha = __float2bfloat16(a);
    __hip_bfloat16 hb = __float2bfloat16(b);
    union { __hip_bfloat16 h; unsigned short s; } ua, ub;
    ua.h = ha; ub.h = hb;
    return (unsigned)ua.s | ((unsigned)ub.s << 16);
}
// async global->LDS, 16B per lane (dest = wave-uniform base + lane*16)
__device__ inline void load_lds16(const void* g, void* l) {
    __builtin_amdgcn_global_load_lds(
        (const __attribute__((address_space(1))) unsigned int*)g,
        (__attribute__((address_space(3))) unsigned int*)l, 16, 0, 0);
}

// B matrix: rows r=2y+cy (256), per-xg cols nl = m*8+xi (96), m=2l+c'
// B[2y, c'=0]=Bxr  B[2y, c'=1]=Bxi  B[2y+1, c'=0]=-Bxi  B[2y+1, c'=1]=Bxr
__global__ __launch_bounds__(256) void b_kernel(const float* __restrict__ img_r,
                                                const float* __restrict__ img_i,
                                                const float* __restrict__ sf_r,
                                                const float* __restrict__ sf_i) {
    int t = blockIdx.x * 256 + threadIdx.x;
    int xg = t / 24576; int rem = t - xg * 24576;
    int r = rem / 96;   int nl = rem - r * 96;
    int y = r >> 1, cy = r & 1;
    int m = nl >> 3, xi = nl & 7;
    int x = xg * 8 + xi, l = m >> 1, cp = m & 1;
    int pix = x * 128 + y;
    float ir = img_r[pix], ii = img_i[pix];
    float sr = sf_r[l * 16384 + pix], si = sf_i[l * 16384 + pix];
    float br = sr * ir - si * ii;
    float bi = sr * ii + si * ir;
    float val = (cy == 0) ? (cp == 0 ? br : bi) : (cp == 0 ? -bi : br);
    int nt = nl >> 4, c16 = nl & 15;
    int kt = r >> 5, lane = c16 | (((r >> 3) & 3) << 4), j = r & 7;
    size_t idx = (size_t)((xg * 6 + nt) * 8 + kt) * 512 + lane * 8 + j;
    g_B[idx] = (unsigned short)bf16_rtne_bits(val);
}

// ---------- fused GEMM: single-bf16, 2 x-groups per block, in-register Ey ----------
// grid (bx 8, mb 256), 256 thr = 4 waves; wave owns rows [mb*128+w*32, +32)
__global__ __launch_bounds__(256, 3) void gemm4_kernel(const float* __restrict__ trj) {
    // [buf][xg2][ntl][512 shorts] = 24 KB
    __shared__ __align__(16) unsigned short ldsB[2][2][6][512];

    const int tid = threadIdx.x;
    const int bx = blockIdx.x, mb = blockIdx.y;
    const int w = tid >> 6, lane = tid & 63;
    const int g = lane >> 4;

    // per-row Ey recurrence state (2 rows per lane: am = 0,1)
    float cr[2], ci[2], d1r[2], d1i[2], d16r[2], d16i[2];
#pragma unroll
    for (int am = 0; am < 2; ++am) {
        int krow = mb * 128 + w * 32 + am * 16 + (lane & 15);
        float ty = trj[krow * 2 + 1];
        float step = -TWOPI * ty * (1.0f / 128.0f);
        sincosf(step * (float)(g * 4 - 64), &ci[am], &cr[am]);
        sincosf(step, &d1i[am], &d1r[am]);
        sincosf(step * 16.0f, &d16i[am], &d16r[am]);
    }

    f32x4 acc[2][2][6];   // [am][xg2][nt]
#pragma unroll
    for (int am = 0; am < 2; ++am)
#pragma unroll
        for (int x2 = 0; x2 < 2; ++x2)
#pragma unroll
            for (int nt = 0; nt < 6; ++nt) acc[am][x2][nt] = (f32x4)0.0f;

    // stage B(kt) for both xg's: 12 segments of 1KB, 3 per wave
    auto stage = [&](int buf, int kt) {
#pragma unroll
        for (int i = 0; i < 3; ++i) {
            int seg = w + i * 4;                 // 0..11, wave-uniform
            int xg2 = seg / 6, ntl = seg - xg2 * 6;
            int xg = bx * 2 + xg2;
            const unsigned short* src = g_B
                + (size_t)((xg * 6 + ntl) * 8 + kt) * 512 + lane * 8;
            load_lds16(src, &ldsB[buf][xg2][ntl][0]);
        }
    };

    stage(0, 0);

    for (int kt = 0; kt < 8; ++kt) {
        __syncthreads();                  // buf[kt&1] loads drained; prev reads done
        if (kt < 7) stage((kt + 1) & 1, kt + 1);

        // A-fragments for this kt (single bf16)
        s16x8 aH[2];
#pragma unroll
        for (int am = 0; am < 2; ++am) {
            float c0 = cr[am], s0 = ci[am];
            float c1 = c0 * d1r[am] - s0 * d1i[am], s1 = c0 * d1i[am] + s0 * d1r[am];
            float c2 = c1 * d1r[am] - s1 * d1i[am], s2 = c1 * d1i[am] + s1 * d1r[am];
            float c3 = c2 * d1r[am] - s2 * d1i[am], s3 = c2 * d1i[am] + s2 * d1r[am];
            cr[am] = c0 * d16r[am] - s0 * d16i[am];
            ci[am] = c0 * d16i[am] + s0 * d16r[am];
            union { s16x8 v; unsigned u[4]; } H;
            H.u[0] = cvt_pk2(c0, s0);
            H.u[1] = cvt_pk2(c1, s1);
            H.u[2] = cvt_pk2(c2, s2);
            H.u[3] = cvt_pk2(c3, s3);
            aH[am] = H.v;
        }

#pragma unroll
        for (int x2 = 0; x2 < 2; ++x2) {
#pragma unroll
            for (int nt = 0; nt < 6; ++nt) {
                s16x8 bH = *(const s16x8*)&ldsB[kt & 1][x2][nt][lane * 8];
#pragma unroll
                for (int am = 0; am < 2; ++am) {
                    acc[am][x2][nt] = __builtin_amdgcn_mfma_f32_16x16x32_bf16(aH[am], bH, acc[am][x2][nt], 0, 0, 0);
                }
            }
        }
    }

    // epilogue: Ex on the fly, reduce over 8 x's per xg, write partial FBx
    // C/D layout: col = lane&15, row = (lane>>4)*4 + reg  [m89-verified, proven R7/R10/R14]
    const int c16 = lane & 15, xi = c16 & 7, cpbit = c16 >> 3;
    const int rowg = lane >> 4;
#pragma unroll
    for (int am = 0; am < 2; ++am) {
#pragma unroll
        for (int reg = 0; reg < 4; ++reg) {
            int krow = mb * 128 + w * 32 + am * 16 + rowg * 4 + reg;
            float tx = trj[krow * 2 + 0];
#pragma unroll
            for (int x2 = 0; x2 < 2; ++x2) {
                int xg = bx * 2 + x2;
                int x = xg * 8 + xi;
                float er, ei;
                sincosf(-TWOPI * tx * ((float)(x - 64) * (1.0f / 128.0f)), &ei, &er);
#pragma unroll
                for (int nt = 0; nt < 6; ++nt) {
                    float tv = acc[am][x2][nt][reg];
                    float pv = __shfl_xor(tv, 8);            // complex partner
                    float v = cpbit ? fmaf(er, tv, ei * pv)  // imag
                                    : fmaf(er, tv, -ei * pv);// real
                    v += __shfl_xor(v, 1);
                    v += __shfl_xor(v, 2);
                    v += __shfl_xor(v, 4);                   // sum over 8 x's
                    if (xi == 0) {
                        int m = nt * 2 + cpbit;              // m = 2l + c'
                        g_part[((size_t)xg * KS + krow) * 12 + m] = v;
                    }
                }
            }
        }
    }
}

// ---------- reduce partials + temporal basis (unchanged, proven) ----------
__global__ __launch_bounds__(256) void combine_kernel(const float* __restrict__ tf_r,
                                                      const float* __restrict__ tf_i,
                                                      float* __restrict__ out) {
    int k = blockIdx.x * blockDim.x + threadIdx.x;
    if (k >= KS) return;

    float fr[LSEG], fi[LSEG];
#pragma unroll
    for (int l = 0; l < LSEG; ++l) { fr[l] = 0.0f; fi[l] = 0.0f; }

#pragma unroll
    for (int s = 0; s < XSPLIT; ++s) {
        const float4* p = (const float4*)(g_part + ((size_t)s * KS + k) * (LSEG * 2));
        float4 a = p[0], b = p[1], c = p[2];
        fr[0] += a.x; fi[0] += a.y; fr[1] += a.z; fi[1] += a.w;
        fr[2] += b.x; fi[2] += b.y; fr[3] += b.z; fi[3] += b.w;
        fr[4] += c.x; fi[4] += c.y; fr[5] += c.z; fi[5] += c.w;
    }

#pragma unroll
    for (int c = 0; c < CC; ++c) {
        float outr = 0.0f, outi = 0.0f;
#pragma unroll
        for (int l = 0; l < LSEG; ++l) {
            float tr = tf_r[((size_t)l * CC + c) * KS + k];
            float ti = tf_i[((size_t)l * CC + c) * KS + k];
            outr = fmaf(fr[l], tr, fmaf(-fi[l], ti, outr));
            outi = fmaf(fr[l], ti, fmaf( fi[l], tr, outi));
        }
        float2* o = (float2*)(out + ((size_t)c * KS + k) * 2);
        *o = make_float2(outr, outi);
    }
}

extern "C" void kernel_launch(void* const* d_in, const int* in_sizes, int n_in,
                              void* d_out, int out_size, void* d_ws, size_t ws_size,
                              hipStream_t stream) {
    const float* img_r = (const float*)d_in[0];
    const float* img_i = (const float*)d_in[1];
    const float* sf_r  = (const float*)d_in[2];
    const float* sf_i  = (const float*)d_in[3];
    const float* tf_r  = (const float*)d_in[4];
    const float* tf_i  = (const float*)d_in[5];
    const float* trj   = (const float*)d_in[6];
    float* out = (float*)d_out;

    b_kernel<<<(16 * 256 * 96) / 256, 256, 0, stream>>>(img_r, img_i, sf_r, sf_i);
    gemm4_kernel<<<dim3(8, 256), 256, 0, stream>>>(trj);
    combine_kernel<<<(KS + 255) / 256, 256, 0, stream>>>(tf_r, tf_i, out);
}